// Round 2
// baseline (183.743 us; speedup 1.0000x reference)
//
#include <hip/hip_runtime.h>

// Circuit_67473936220746, round 7: persistent 2-h blocks (256 x 1024), state
// prefetch for h1 into registers during h0's pass B, uniform sigma-swizzle on
// all LDS slots (2-way max on writes, conflict-free reads), prep merged into
// one launch (WA = (W2*W1)*W0 chained, WB folded in). 2 launches total.
//
// State per high-index h (bits 14-22): T[ch][b][a] (b = bits 7-13, a = bits 0-6).
//   Pass A: mid[kp=ch'*128+ka][b] = sum_{ch,a} WA[kp][ch*128+a] * T[ch][b][a]
//   Pass B: out[ch''][kb][ka]     = sum_{ch',b} WB[ch''*128+kb][ch'*128+b] * mid[ch'*128+ka][b]
// WA = W2*W1*W0 (fp32 on device), WB = W3, Wg = [[Ui,Ur],[Ur,-Ui]].
// 3-term bf16 split both passes (ah*bh + al*bh + ah*bl).
//
// MFMA 16x16x32 bf16 layouts (HW-verified):
//   A: m = lane&15, k = (lane>>4)*8 + j (16B/lane contiguous)
//   B: n = lane&15, k = (lane>>4)*8 + j
//   C/D: col(n) = lane&15, row(m) = (lane>>4)*4 + reg
//
// Frag-linear storage: frag(tile,ks) = 64 slots x 8 shorts; lane reads one 16B
// slot. LDS physical slot = slot ^ ((slot>>3)&6) ^ (frag&7): folds slot bits
// 4-5 into bank bits so staging/MID ds_write_b64 drop to 2-way (free); reads
// remain a per-frag bijection over 64 slots = conflict-free b128.

typedef __attribute__((ext_vector_type(8))) short bf16x8;
typedef __attribute__((ext_vector_type(4))) short bf16x4;
typedef __attribute__((ext_vector_type(4))) float f32x4;

static constexpr int NSTATE = 1 << 23;

// truncation split: x ~= bf16(h) + bf16(l), rel err ~2^-16
__device__ inline void tsplit(float x, unsigned short& h, unsigned short& l) {
    unsigned int u = __float_as_uint(x);
    h = (unsigned short)(u >> 16);
    float hf = __uint_as_float(u & 0xFFFF0000u);
    l = (unsigned short)(__float_as_uint(x - hf) >> 16);
}

// RNE split (weights, prep only)
__device__ inline void rsplit(float x, unsigned short& h, unsigned short& l) {
    unsigned int u = __float_as_uint(x);
    unsigned int r = (u + 0x7FFFu + ((u >> 16) & 1u)) >> 16;
    h = (unsigned short)r;
    float hf = __uint_as_float(r << 16);
    unsigned int u2 = __float_as_uint(x - hf);
    l = (unsigned short)((u2 + 0x7FFFu + ((u2 >> 16) & 1u)) >> 16);
}

// signed block-matrix element: Wg[kp][ap], Ug -> U[g][0][0][0]
__device__ inline float wElem(const float* __restrict__ Ug, int kp, int ap) {
    const int co = kp >> 7, ci = ap >> 7;
    const float v = Ug[((co == ci) ? 16384 : 0) + (kp & 127) * 128 + (ap & 127)];
    return (co & ci) ? -v : v;
}

// frag-linear scatter offset (in shorts) for element (row i, col t) of a 256x256 W
__device__ inline int fragOff(int i, int t) {
    const int frag = (i >> 4) * 8 + (t >> 5);
    const int slot = (i & 15) + 16 * ((t >> 3) & 3);
    return frag * 512 + slot * 8 + (t & 7);
}

// LDS slot swizzle: involution per frag; spreads slot bits 4-5 into bank bits
__device__ inline int slotSwz(int frag, int slot) {
    return slot ^ ((slot >> 3) & 6) ^ (frag & 7);
}

// state/MID LDS offset (in shorts) for state element (row b, col kk)
__device__ inline int sOff(int b, int kk) {
    const int frag = (b >> 4) * 8 + (kk >> 5);
    const int slot = (b & 15) + 16 * ((kk >> 3) & 3);
    return frag * 512 + slotSwz(frag, slot) * 8 + (kk & 7);
}

// ---- single prep launch ----
// blocks 0..255:  WA row i = ((W2*W1)*W0)[i], rsplit + frag scatter
// blocks 256..511: WB row i = W3g[i], rsplit + frag scatter
__global__ __launch_bounds__(256)
void prep_all(const float* __restrict__ U,
              unsigned short* __restrict__ WAh, unsigned short* __restrict__ WAl,
              unsigned short* __restrict__ WBh, unsigned short* __restrict__ WBl) {
    __shared__ float Arow[256];
    const int t = threadIdx.x;
    if (blockIdx.x < 256) {
        const int i = blockIdx.x;
        Arow[t] = wElem(U + 2 * 32768, i, t);               // W2 row i
        __syncthreads();
        float r = 0.f;
        #pragma unroll 8
        for (int k = 0; k < 256; ++k)
            r = fmaf(Arow[k], wElem(U + 32768, k, t), r);   // (W2*W1)[i][t]
        __syncthreads();
        Arow[t] = r;
        __syncthreads();
        float s = 0.f;
        #pragma unroll 8
        for (int k = 0; k < 256; ++k)
            s = fmaf(Arow[k], wElem(U, k, t), s);           // * W0
        unsigned short h, l;
        rsplit(s, h, l);
        const int off = fragOff(i, t);
        WAh[off] = h; WAl[off] = l;
    } else {
        const int i = blockIdx.x - 256;
        unsigned short h, l;
        rsplit(wElem(U + 3 * 32768, i, t), h, l);
        const int off = fragOff(i, t);
        WBh[off] = h; WBl[off] = l;
    }
}

// ---- fused main: 256 persistent blocks (h = 2*bx, 2*bx+1) x 1024 threads ----
__global__ __launch_bounds__(1024, 4)
void fused4(const float* __restrict__ src, float* __restrict__ dst,
            const unsigned short* __restrict__ WAh, const unsigned short* __restrict__ WAl,
            const unsigned short* __restrict__ WBh, const unsigned short* __restrict__ WBl)
{
    // 64 KB each: state-high/low during pass A, MID-high/low during pass B
    __shared__ unsigned short Sh[32768];
    __shared__ unsigned short Sl[32768];

    const int t    = threadIdx.x;
    const int lane = t & 63;
    const int w    = t >> 6;            // 0..15
    const int col  = lane & 15, quad = lane >> 4;
    const int mg   = w >> 3;            // m-group (2)
    const int ng   = w & 7;             // n-group (8)
    const int r0   = t >> 5;            // staging row-within-32
    const int kkl  = (t & 31) * 4;      // staging float4 column

    float4 pf[8];                        // prefetched h1 state

    #pragma unroll
    for (int hh = 0; hh < 2; ++hh) {
        const size_t hbase = (size_t)(blockIdx.x * 2 + hh) * 16384;

        // ============ STAGE: fp32 -> split bf16 h/l -> LDS frag-linear ============
        {
            float4 v[8];
            if (hh == 0) {
                #pragma unroll
                for (int i = 0; i < 8; ++i) {
                    const int ch = i >> 2;
                    const int b  = (i & 3) * 32 + r0;
                    v[i] = *(const float4*)(src + (size_t)ch * NSTATE + hbase + (size_t)b * 128 + kkl);
                }
            } else {
                #pragma unroll
                for (int i = 0; i < 8; ++i) v[i] = pf[i];
            }
            #pragma unroll
            for (int i = 0; i < 8; ++i) {
                const int ch = i >> 2;
                const int b  = (i & 3) * 32 + r0;
                const int kk = ch * 128 + kkl;
                unsigned short h0, h1, h2, h3, l0, l1, l2s, l3;
                tsplit(v[i].x, h0, l0); tsplit(v[i].y, h1, l1);
                tsplit(v[i].z, h2, l2s); tsplit(v[i].w, h3, l3);
                const int off = sOff(b, kk);            // kk&7 in {0,4}: 8B aligned
                bf16x4 hv = { (short)h0, (short)h1, (short)h2, (short)h3 };
                bf16x4 lv = { (short)l0, (short)l1, (short)l2s, (short)l3 };
                *(bf16x4*)&Sh[off] = hv;
                *(bf16x4*)&Sl[off] = lv;
            }
        }
        __syncthreads();

        // ============ PASS A ============
        // m = b: 8 tiles, mg owns 4; n = kp: 16 tiles, ng owns 2.
        f32x4 acc[4][2];
        #pragma unroll
        for (int mi = 0; mi < 4; ++mi)
            #pragma unroll
            for (int l2 = 0; l2 < 2; ++l2) acc[mi][l2] = (f32x4)0.f;

        #pragma unroll 2
        for (int ks = 0; ks < 8; ++ks) {
            bf16x8 ah[4], al[4];
            #pragma unroll
            for (int mi = 0; mi < 4; ++mi) {
                const int fr = (mg * 4 + mi) * 8 + ks;
                const int fo = fr * 512 + slotSwz(fr, lane) * 8;
                ah[mi] = *(const bf16x8*)&Sh[fo];
                al[mi] = *(const bf16x8*)&Sl[fo];
            }
            bf16x8 bh[2], bl[2];
            #pragma unroll
            for (int l2 = 0; l2 < 2; ++l2) {
                const int fo = ((ng * 2 + l2) * 8 + ks) * 512 + lane * 8;
                bh[l2] = *(const bf16x8*)(WAh + fo);
                bl[l2] = *(const bf16x8*)(WAl + fo);
            }
            #pragma unroll
            for (int l2 = 0; l2 < 2; ++l2)
                #pragma unroll
                for (int mi = 0; mi < 4; ++mi) {
                    acc[mi][l2] = __builtin_amdgcn_mfma_f32_16x16x32_bf16(ah[mi], bh[l2], acc[mi][l2], 0, 0, 0);
                    acc[mi][l2] = __builtin_amdgcn_mfma_f32_16x16x32_bf16(al[mi], bh[l2], acc[mi][l2], 0, 0, 0);
                    acc[mi][l2] = __builtin_amdgcn_mfma_f32_16x16x32_bf16(ah[mi], bl[l2], acc[mi][l2], 0, 0, 0);
                }
        }
        __syncthreads();    // all state reads complete before MID overwrites

        // ---- write MID pre-split to LDS frag layout (overwrites state region) ----
        // element (b = mt*16 + quad*4 + r, kp = nt*16 + col):
        //   frag2 = (nt&7)*8 + (nt>>3)*4 + (mt>>1); slot = col + 16*((mt*2+(quad>>1))&3)
        #pragma unroll
        for (int mi = 0; mi < 4; ++mi) {
            const int mt  = mg * 4 + mi;
            const int oct = (mt * 2 + (quad >> 1)) & 3;
            #pragma unroll
            for (int l2 = 0; l2 < 2; ++l2) {
                const int nt    = ng * 2 + l2;
                const int frag2 = (nt & 7) * 8 + (nt >> 3) * 4 + (mt >> 1);
                const int slot2 = col + 16 * oct;
                const int soff  = frag2 * 512 + slotSwz(frag2, slot2) * 8 + (quad & 1) * 4;
                unsigned short hhs[4], lls[4];
                #pragma unroll
                for (int r = 0; r < 4; ++r) tsplit(acc[mi][l2][r], hhs[r], lls[r]);
                bf16x4 hv = { (short)hhs[0], (short)hhs[1], (short)hhs[2], (short)hhs[3] };
                bf16x4 lv = { (short)lls[0], (short)lls[1], (short)lls[2], (short)lls[3] };
                *(bf16x4*)&Sh[soff] = hv;
                *(bf16x4*)&Sl[soff] = lv;
            }
        }
        __syncthreads();

        // ============ PASS B ============
        // issue h1 state prefetch first so HBM latency hides under pass-B MFMA
        if (hh == 0) {
            const size_t hb1 = (size_t)(blockIdx.x * 2 + 1) * 16384;
            #pragma unroll
            for (int i = 0; i < 8; ++i) {
                const int ch = i >> 2;
                const int b  = (i & 3) * 32 + r0;
                pf[i] = *(const float4*)(src + (size_t)ch * NSTATE + hb1 + (size_t)b * 128 + kkl);
            }
        }

        // m2 = ka: 8 tiles, mg owns 4; n2 = kp2: 16 tiles, ng owns 2.
        f32x4 acc2[4][2];
        #pragma unroll
        for (int mi = 0; mi < 4; ++mi)
            #pragma unroll
            for (int nj = 0; nj < 2; ++nj) acc2[mi][nj] = (f32x4)0.f;

        #pragma unroll 2
        for (int ks2 = 0; ks2 < 8; ++ks2) {
            bf16x8 a2h[4], a2l[4];
            #pragma unroll
            for (int mi = 0; mi < 4; ++mi) {
                const int fr = (mg * 4 + mi) * 8 + ks2;
                const int fo = fr * 512 + slotSwz(fr, lane) * 8;
                a2h[mi] = *(const bf16x8*)&Sh[fo];
                a2l[mi] = *(const bf16x8*)&Sl[fo];
            }
            bf16x8 bh2[2], bl2[2];
            #pragma unroll
            for (int nj = 0; nj < 2; ++nj) {
                const int fo = ((ng * 2 + nj) * 8 + ks2) * 512 + lane * 8;
                bh2[nj] = *(const bf16x8*)(WBh + fo);
                bl2[nj] = *(const bf16x8*)(WBl + fo);
            }
            #pragma unroll
            for (int nj = 0; nj < 2; ++nj)
                #pragma unroll
                for (int mi = 0; mi < 4; ++mi) {
                    acc2[mi][nj] = __builtin_amdgcn_mfma_f32_16x16x32_bf16(a2h[mi], bh2[nj], acc2[mi][nj], 0, 0, 0);
                    acc2[mi][nj] = __builtin_amdgcn_mfma_f32_16x16x32_bf16(a2l[mi], bh2[nj], acc2[mi][nj], 0, 0, 0);
                    acc2[mi][nj] = __builtin_amdgcn_mfma_f32_16x16x32_bf16(a2h[mi], bl2[nj], acc2[mi][nj], 0, 0, 0);
                }
        }

        // MID reads done before h1 stage overwrites LDS
        if (hh == 0) __syncthreads();

        // ---- epilogue: out[ch''][kb][ka], float4 over ka (coalesced) ----
        #pragma unroll
        for (int nj = 0; nj < 2; ++nj) {
            const int kp2  = (ng * 2 + nj) * 16 + col;
            const int chpp = kp2 >> 7, kb = kp2 & 127;
            float* o = dst + (size_t)chpp * NSTATE + hbase + (size_t)kb * 128;
            #pragma unroll
            for (int mi = 0; mi < 4; ++mi) {
                const int ka = (mg * 4 + mi) * 16 + quad * 4;
                *(float4*)(o + ka) = *(float4*)&acc2[mi][nj];
            }
        }
    }
}

extern "C" void kernel_launch(void* const* d_in, const int* in_sizes, int n_in,
                              void* d_out, int out_size, void* d_ws, size_t ws_size,
                              hipStream_t stream) {
    const float* state = (const float*)d_in[0];   // (2, 2^23)
    const float* U     = (const float*)d_in[1];   // (4, 2, 128, 128)
    float* out = (float*)d_out;

    // ws: WAh WAl WBh WBl (128 KB each, frag-linear bf16)
    unsigned short* WAh = (unsigned short*)d_ws;
    unsigned short* WAl = WAh + 65536;
    unsigned short* WBh = WAh + 2 * 65536;
    unsigned short* WBl = WAh + 3 * 65536;

    prep_all<<<512, 256, 0, stream>>>(U, WAh, WAl, WBh, WBl);
    fused4  <<<256, 1024, 0, stream>>>(state, out, WAh, WAl, WBh, WBl);
}

// Round 3
// 170.163 us; speedup vs baseline: 1.0798x; 1.0798x over previous
//
#include <hip/hip_runtime.h>

// Circuit_67473936220746, round 8: back to 512 blocks x 1 h (no register
// prefetch -- round 7's pf[] spilled to scratch, +50 MB HBM). Both pass
// k-loops fully unrolled with register double-buffer of the bh W-operand
// (loaded one iteration ahead), bl loaded just-in-time, MFMAs term-major so
// same-accumulator dependency distance is 8 instead of 1. Sigma-swizzle kept
// (bank conflicts 2.1M -> 524K last round). Numerics bit-identical.
//
// State per high-index h (bits 14-22): T[ch][b][a] (b = bits 7-13, a = bits 0-6).
//   Pass A: mid[kp=ch'*128+ka][b] = sum_{ch,a} WA[kp][ch*128+a] * T[ch][b][a]
//   Pass B: out[ch''][kb][ka]     = sum_{ch',b} WB[ch''*128+kb][ch'*128+b] * mid[ch'*128+ka][b]
// WA = (W2*W1)*W0 (fp32 on device), WB = W3, Wg = [[Ui,Ur],[Ur,-Ui]].
// 3-term bf16 split both passes (ah*bh + al*bh + ah*bl).
//
// MFMA 16x16x32 bf16 layouts (HW-verified):
//   A: m = lane&15, k = (lane>>4)*8 + j (16B/lane contiguous)
//   B: n = lane&15, k = (lane>>4)*8 + j
//   C/D: col(n) = lane&15, row(m) = (lane>>4)*4 + reg
//
// Frag-linear storage: frag(tile,ks) = 64 slots x 8 shorts; lane reads one 16B
// slot. LDS physical slot = slot ^ ((slot>>3)&6) ^ (frag&7): staging/MID
// ds_write_b64 drop to 2-way (free); reads remain a per-frag bijection over
// 64 slots = conflict-free b128.

typedef __attribute__((ext_vector_type(8))) short bf16x8;
typedef __attribute__((ext_vector_type(4))) short bf16x4;
typedef __attribute__((ext_vector_type(4))) float f32x4;

static constexpr int NSTATE = 1 << 23;

// truncation split: x ~= bf16(h) + bf16(l), rel err ~2^-16
__device__ inline void tsplit(float x, unsigned short& h, unsigned short& l) {
    unsigned int u = __float_as_uint(x);
    h = (unsigned short)(u >> 16);
    float hf = __uint_as_float(u & 0xFFFF0000u);
    l = (unsigned short)(__float_as_uint(x - hf) >> 16);
}

// RNE split (weights, prep only)
__device__ inline void rsplit(float x, unsigned short& h, unsigned short& l) {
    unsigned int u = __float_as_uint(x);
    unsigned int r = (u + 0x7FFFu + ((u >> 16) & 1u)) >> 16;
    h = (unsigned short)r;
    float hf = __uint_as_float(r << 16);
    unsigned int u2 = __float_as_uint(x - hf);
    l = (unsigned short)((u2 + 0x7FFFu + ((u2 >> 16) & 1u)) >> 16);
}

// signed block-matrix element: Wg[kp][ap], Ug -> U[g][0][0][0]
__device__ inline float wElem(const float* __restrict__ Ug, int kp, int ap) {
    const int co = kp >> 7, ci = ap >> 7;
    const float v = Ug[((co == ci) ? 16384 : 0) + (kp & 127) * 128 + (ap & 127)];
    return (co & ci) ? -v : v;
}

// frag-linear scatter offset (in shorts) for element (row i, col t) of a 256x256 W
__device__ inline int fragOff(int i, int t) {
    const int frag = (i >> 4) * 8 + (t >> 5);
    const int slot = (i & 15) + 16 * ((t >> 3) & 3);
    return frag * 512 + slot * 8 + (t & 7);
}

// LDS slot swizzle: involution per frag; spreads slot bits 4-5 into bank bits
__device__ inline int slotSwz(int frag, int slot) {
    return slot ^ ((slot >> 3) & 6) ^ (frag & 7);
}

// state/MID LDS offset (in shorts) for state element (row b, col kk)
__device__ inline int sOff(int b, int kk) {
    const int frag = (b >> 4) * 8 + (kk >> 5);
    const int slot = (b & 15) + 16 * ((kk >> 3) & 3);
    return frag * 512 + slotSwz(frag, slot) * 8 + (kk & 7);
}

// ---- single prep launch ----
// blocks 0..255:  WA row i = ((W2*W1)*W0)[i], rsplit + frag scatter
// blocks 256..511: WB row i = W3g[i], rsplit + frag scatter
__global__ __launch_bounds__(256)
void prep_all(const float* __restrict__ U,
              unsigned short* __restrict__ WAh, unsigned short* __restrict__ WAl,
              unsigned short* __restrict__ WBh, unsigned short* __restrict__ WBl) {
    __shared__ float Arow[256];
    const int t = threadIdx.x;
    if (blockIdx.x < 256) {
        const int i = blockIdx.x;
        Arow[t] = wElem(U + 2 * 32768, i, t);               // W2 row i
        __syncthreads();
        float r = 0.f;
        #pragma unroll 8
        for (int k = 0; k < 256; ++k)
            r = fmaf(Arow[k], wElem(U + 32768, k, t), r);   // (W2*W1)[i][t]
        __syncthreads();
        Arow[t] = r;
        __syncthreads();
        float s = 0.f;
        #pragma unroll 8
        for (int k = 0; k < 256; ++k)
            s = fmaf(Arow[k], wElem(U, k, t), s);           // * W0
        unsigned short h, l;
        rsplit(s, h, l);
        const int off = fragOff(i, t);
        WAh[off] = h; WAl[off] = l;
    } else {
        const int i = blockIdx.x - 256;
        unsigned short h, l;
        rsplit(wElem(U + 3 * 32768, i, t), h, l);
        const int off = fragOff(i, t);
        WBh[off] = h; WBl[off] = l;
    }
}

// ---- fused main: 512 blocks (one per h) x 1024 threads (16 waves) ----
__global__ __launch_bounds__(1024, 4)
void fused5(const float* __restrict__ src, float* __restrict__ dst,
            const unsigned short* __restrict__ WAh, const unsigned short* __restrict__ WAl,
            const unsigned short* __restrict__ WBh, const unsigned short* __restrict__ WBl)
{
    // 64 KB each: state-high/low during pass A, MID-high/low during pass B
    __shared__ unsigned short Sh[32768];
    __shared__ unsigned short Sl[32768];

    const int t    = threadIdx.x;
    const int lane = t & 63;
    const int w    = t >> 6;            // 0..15
    const int col  = lane & 15, quad = lane >> 4;
    const int mg   = w >> 3;            // m-group (2)
    const int ng   = w & 7;             // n-group (8)
    const size_t hbase = (size_t)blockIdx.x * 16384;

    // ============ STAGE: fp32 -> split bf16 h/l -> LDS frag-linear ============
    {
        const int r0  = t >> 5;
        const int kkl = (t & 31) * 4;
        float4 v[8];
        #pragma unroll
        for (int i = 0; i < 8; ++i) {
            const int ch = i >> 2;
            const int b  = (i & 3) * 32 + r0;
            v[i] = *(const float4*)(src + (size_t)ch * NSTATE + hbase + (size_t)b * 128 + kkl);
        }
        #pragma unroll
        for (int i = 0; i < 8; ++i) {
            const int ch = i >> 2;
            const int b  = (i & 3) * 32 + r0;
            const int kk = ch * 128 + kkl;
            unsigned short h0, h1, h2, h3, l0, l1, l2s, l3;
            tsplit(v[i].x, h0, l0); tsplit(v[i].y, h1, l1);
            tsplit(v[i].z, h2, l2s); tsplit(v[i].w, h3, l3);
            const int off = sOff(b, kk);            // kk&7 in {0,4}: 8B aligned
            bf16x4 hv = { (short)h0, (short)h1, (short)h2, (short)h3 };
            bf16x4 lv = { (short)l0, (short)l1, (short)l2s, (short)l3 };
            *(bf16x4*)&Sh[off] = hv;
            *(bf16x4*)&Sl[off] = lv;
        }
    }
    __syncthreads();

    // ============ PASS A ============
    // m = b: 8 tiles, mg owns 4; n = kp: 16 tiles, ng owns 2.
    f32x4 acc[4][2];
    #pragma unroll
    for (int mi = 0; mi < 4; ++mi)
        #pragma unroll
        for (int l2 = 0; l2 < 2; ++l2) acc[mi][l2] = (f32x4)0.f;

    {
        // register double-buffer for bh (one k-step ahead); bl just-in-time
        bf16x8 bh[2][2];
        #pragma unroll
        for (int l2 = 0; l2 < 2; ++l2) {
            const int fo = ((ng * 2 + l2) * 8 + 0) * 512 + lane * 8;
            bh[0][l2] = *(const bf16x8*)(WAh + fo);
        }
        #pragma unroll
        for (int ks = 0; ks < 8; ++ks) {
            const int cur = ks & 1, nxt = cur ^ 1;
            bf16x8 ah[4], al[4];
            #pragma unroll
            for (int mi = 0; mi < 4; ++mi) {
                const int fr = (mg * 4 + mi) * 8 + ks;
                const int fo = fr * 512 + slotSwz(fr, lane) * 8;
                ah[mi] = *(const bf16x8*)&Sh[fo];
                al[mi] = *(const bf16x8*)&Sl[fo];
            }
            bf16x8 bl[2];
            #pragma unroll
            for (int l2 = 0; l2 < 2; ++l2) {
                const int fo = ((ng * 2 + l2) * 8 + ks) * 512 + lane * 8;
                bl[l2] = *(const bf16x8*)(WAl + fo);        // used at term 3
            }
            if (ks < 7) {
                #pragma unroll
                for (int l2 = 0; l2 < 2; ++l2) {
                    const int fo = ((ng * 2 + l2) * 8 + (ks + 1)) * 512 + lane * 8;
                    bh[nxt][l2] = *(const bf16x8*)(WAh + fo);
                }
            }
            // term-major: same-acc updates stay in order (ah*bh, al*bh, ah*bl)
            #pragma unroll
            for (int l2 = 0; l2 < 2; ++l2)
                #pragma unroll
                for (int mi = 0; mi < 4; ++mi)
                    acc[mi][l2] = __builtin_amdgcn_mfma_f32_16x16x32_bf16(ah[mi], bh[cur][l2], acc[mi][l2], 0, 0, 0);
            #pragma unroll
            for (int l2 = 0; l2 < 2; ++l2)
                #pragma unroll
                for (int mi = 0; mi < 4; ++mi)
                    acc[mi][l2] = __builtin_amdgcn_mfma_f32_16x16x32_bf16(al[mi], bh[cur][l2], acc[mi][l2], 0, 0, 0);
            #pragma unroll
            for (int l2 = 0; l2 < 2; ++l2)
                #pragma unroll
                for (int mi = 0; mi < 4; ++mi)
                    acc[mi][l2] = __builtin_amdgcn_mfma_f32_16x16x32_bf16(ah[mi], bl[l2], acc[mi][l2], 0, 0, 0);
        }
    }
    __syncthreads();    // all state reads complete before MID overwrites

    // ---- write MID pre-split to LDS frag layout (overwrites state region) ----
    // element (b = mt*16 + quad*4 + r, kp = nt*16 + col):
    //   frag2 = (nt&7)*8 + (nt>>3)*4 + (mt>>1); slot = col + 16*((mt*2+(quad>>1))&3)
    #pragma unroll
    for (int mi = 0; mi < 4; ++mi) {
        const int mt  = mg * 4 + mi;
        const int oct = (mt * 2 + (quad >> 1)) & 3;
        #pragma unroll
        for (int l2 = 0; l2 < 2; ++l2) {
            const int nt    = ng * 2 + l2;
            const int frag2 = (nt & 7) * 8 + (nt >> 3) * 4 + (mt >> 1);
            const int slot2 = col + 16 * oct;
            const int soff  = frag2 * 512 + slotSwz(frag2, slot2) * 8 + (quad & 1) * 4;
            unsigned short hhs[4], lls[4];
            #pragma unroll
            for (int r = 0; r < 4; ++r) tsplit(acc[mi][l2][r], hhs[r], lls[r]);
            bf16x4 hv = { (short)hhs[0], (short)hhs[1], (short)hhs[2], (short)hhs[3] };
            bf16x4 lv = { (short)lls[0], (short)lls[1], (short)lls[2], (short)lls[3] };
            *(bf16x4*)&Sh[soff] = hv;
            *(bf16x4*)&Sl[soff] = lv;
        }
    }
    __syncthreads();

    // ============ PASS B ============
    // m2 = ka: 8 tiles, mg owns 4; n2 = kp2: 16 tiles, ng owns 2.
    f32x4 acc2[4][2];
    #pragma unroll
    for (int mi = 0; mi < 4; ++mi)
        #pragma unroll
        for (int nj = 0; nj < 2; ++nj) acc2[mi][nj] = (f32x4)0.f;

    {
        bf16x8 bh2[2][2];
        #pragma unroll
        for (int nj = 0; nj < 2; ++nj) {
            const int fo = ((ng * 2 + nj) * 8 + 0) * 512 + lane * 8;
            bh2[0][nj] = *(const bf16x8*)(WBh + fo);
        }
        #pragma unroll
        for (int ks2 = 0; ks2 < 8; ++ks2) {
            const int cur = ks2 & 1, nxt = cur ^ 1;
            bf16x8 a2h[4], a2l[4];
            #pragma unroll
            for (int mi = 0; mi < 4; ++mi) {
                const int fr = (mg * 4 + mi) * 8 + ks2;
                const int fo = fr * 512 + slotSwz(fr, lane) * 8;
                a2h[mi] = *(const bf16x8*)&Sh[fo];
                a2l[mi] = *(const bf16x8*)&Sl[fo];
            }
            bf16x8 bl2[2];
            #pragma unroll
            for (int nj = 0; nj < 2; ++nj) {
                const int fo = ((ng * 2 + nj) * 8 + ks2) * 512 + lane * 8;
                bl2[nj] = *(const bf16x8*)(WBl + fo);
            }
            if (ks2 < 7) {
                #pragma unroll
                for (int nj = 0; nj < 2; ++nj) {
                    const int fo = ((ng * 2 + nj) * 8 + (ks2 + 1)) * 512 + lane * 8;
                    bh2[nxt][nj] = *(const bf16x8*)(WBh + fo);
                }
            }
            #pragma unroll
            for (int nj = 0; nj < 2; ++nj)
                #pragma unroll
                for (int mi = 0; mi < 4; ++mi)
                    acc2[mi][nj] = __builtin_amdgcn_mfma_f32_16x16x32_bf16(a2h[mi], bh2[cur][nj], acc2[mi][nj], 0, 0, 0);
            #pragma unroll
            for (int nj = 0; nj < 2; ++nj)
                #pragma unroll
                for (int mi = 0; mi < 4; ++mi)
                    acc2[mi][nj] = __builtin_amdgcn_mfma_f32_16x16x32_bf16(a2l[mi], bh2[cur][nj], acc2[mi][nj], 0, 0, 0);
            #pragma unroll
            for (int nj = 0; nj < 2; ++nj)
                #pragma unroll
                for (int mi = 0; mi < 4; ++mi)
                    acc2[mi][nj] = __builtin_amdgcn_mfma_f32_16x16x32_bf16(a2h[mi], bl2[nj], acc2[mi][nj], 0, 0, 0);
        }
    }

    // ---- epilogue: out[ch''][kb][ka], float4 over ka (coalesced) ----
    #pragma unroll
    for (int nj = 0; nj < 2; ++nj) {
        const int kp2  = (ng * 2 + nj) * 16 + col;
        const int chpp = kp2 >> 7, kb = kp2 & 127;
        float* o = dst + (size_t)chpp * NSTATE + hbase + (size_t)kb * 128;
        #pragma unroll
        for (int mi = 0; mi < 4; ++mi) {
            const int ka = (mg * 4 + mi) * 16 + quad * 4;
            *(float4*)(o + ka) = *(float4*)&acc2[mi][nj];
        }
    }
}

extern "C" void kernel_launch(void* const* d_in, const int* in_sizes, int n_in,
                              void* d_out, int out_size, void* d_ws, size_t ws_size,
                              hipStream_t stream) {
    const float* state = (const float*)d_in[0];   // (2, 2^23)
    const float* U     = (const float*)d_in[1];   // (4, 2, 128, 128)
    float* out = (float*)d_out;

    // ws: WAh WAl WBh WBl (128 KB each, frag-linear bf16)
    unsigned short* WAh = (unsigned short*)d_ws;
    unsigned short* WAl = WAh + 65536;
    unsigned short* WBh = WAh + 2 * 65536;
    unsigned short* WBl = WAh + 3 * 65536;

    prep_all<<<512, 256, 0, stream>>>(U, WAh, WAl, WBh, WBl);
    fused5 <<<512, 1024, 0, stream>>>(state, out, WAh, WAl, WBh, WBl);
}

// Round 4
// 167.508 us; speedup vs baseline: 1.0969x; 1.0158x over previous
//
#include <hip/hip_runtime.h>

// Circuit_67473936220746, round 9: DMA staging (global_load_lds width=16) of
// raw fp32 state into LDS with source-side XOR swizzle (linear LDS dest),
// ch-split stage barriers so half the HBM fetch hides under pass-A ks0-3,
// bf16 split moved to A-frag read time (bit-identical tsplit), wave grid
// rebalanced 2x8 -> 4x4 (mg=w&3 so W-sharing waves sit on the 4 SIMDs in
// lockstep, W stays L1-hot; LDS A-read redundancy 8x -> 4x). MID path
// (pre-split bf16 h/l, slotSwz frag-linear) unchanged and aliases the state
// region. Numerics bit-identical to round 8.
//
// State per high-index h (bits 14-22): T[ch][b][a] (b = bits 7-13, a = bits 0-6).
//   Pass A: mid[kp=ch'*128+ka][b] = sum_{ch,a} WA[kp][ch*128+a] * T[ch][b][a]
//   Pass B: out[ch''][kb][ka]     = sum_{ch',b} WB[ch''*128+kb][ch'*128+b] * mid[ch'*128+ka][b]
// WA = (W2*W1)*W0 (fp32 on device), WB = W3, Wg = [[Ui,Ur],[Ur,-Ui]].
// 3-term bf16 split both passes (ah*bh + al*bh + ah*bl).
//
// MFMA 16x16x32 bf16 layouts (HW-verified):
//   A: m = lane&15, k = (lane>>4)*8 + j (16B/lane contiguous)
//   B: n = lane&15, k = (lane>>4)*8 + j
//   C/D: col(n) = lane&15, row(m) = (lane>>4)*4 + reg
//
// State LDS (fp32, 256 rows r = ch*128+b x 512 B): physical byte-in-row =
// logical ^ ((r&7)<<4). DMA writes are linear (HW: base + lane*16); the
// inverse permutation is applied to the per-lane GLOBAL source address.
// Reads XOR the same mask; 16-B chunks stay contiguous (mask bits >= 4).

typedef __attribute__((ext_vector_type(8))) short bf16x8;
typedef __attribute__((ext_vector_type(4))) short bf16x4;
typedef __attribute__((ext_vector_type(4))) float f32x4;

static constexpr int NSTATE = 1 << 23;

// truncation split: x ~= bf16(h) + bf16(l), rel err ~2^-16
__device__ inline void tsplit(float x, unsigned short& h, unsigned short& l) {
    unsigned int u = __float_as_uint(x);
    h = (unsigned short)(u >> 16);
    float hf = __uint_as_float(u & 0xFFFF0000u);
    l = (unsigned short)(__float_as_uint(x - hf) >> 16);
}

__device__ inline void split8(const float* xv, bf16x8& hv, bf16x8& lv) {
    #pragma unroll
    for (int i = 0; i < 8; ++i) {
        unsigned short h, l;
        tsplit(xv[i], h, l);
        hv[i] = (short)h; lv[i] = (short)l;
    }
}

// RNE split (weights, prep only)
__device__ inline void rsplit(float x, unsigned short& h, unsigned short& l) {
    unsigned int u = __float_as_uint(x);
    unsigned int r = (u + 0x7FFFu + ((u >> 16) & 1u)) >> 16;
    h = (unsigned short)r;
    float hf = __uint_as_float(r << 16);
    unsigned int u2 = __float_as_uint(x - hf);
    l = (unsigned short)((u2 + 0x7FFFu + ((u2 >> 16) & 1u)) >> 16);
}

// signed block-matrix element: Wg[kp][ap], Ug -> U[g][0][0][0]
__device__ inline float wElem(const float* __restrict__ Ug, int kp, int ap) {
    const int co = kp >> 7, ci = ap >> 7;
    const float v = Ug[((co == ci) ? 16384 : 0) + (kp & 127) * 128 + (ap & 127)];
    return (co & ci) ? -v : v;
}

// frag-linear scatter offset (in shorts) for element (row i, col t) of a 256x256 W
__device__ inline int fragOff(int i, int t) {
    const int frag = (i >> 4) * 8 + (t >> 5);
    const int slot = (i & 15) + 16 * ((t >> 3) & 3);
    return frag * 512 + slot * 8 + (t & 7);
}

// LDS slot swizzle for MID (involution per frag)
__device__ inline int slotSwz(int frag, int slot) {
    return slot ^ ((slot >> 3) & 6) ^ (frag & 7);
}

// async 16B/lane global -> LDS (lds dest = wave-uniform base + lane*16)
__device__ inline void dma16(const float* gp, float* lp) {
    __builtin_amdgcn_global_load_lds(
        (const __attribute__((address_space(1))) unsigned int*)gp,
        (__attribute__((address_space(3))) unsigned int*)lp,
        16, 0, 0);
}

// ---- single prep launch ----
// blocks 0..255:  WA row i = ((W2*W1)*W0)[i], rsplit + frag scatter
// blocks 256..511: WB row i = W3g[i], rsplit + frag scatter
__global__ __launch_bounds__(256)
void prep_all(const float* __restrict__ U,
              unsigned short* __restrict__ WAh, unsigned short* __restrict__ WAl,
              unsigned short* __restrict__ WBh, unsigned short* __restrict__ WBl) {
    __shared__ float Arow[256];
    const int t = threadIdx.x;
    if (blockIdx.x < 256) {
        const int i = blockIdx.x;
        Arow[t] = wElem(U + 2 * 32768, i, t);               // W2 row i
        __syncthreads();
        float r = 0.f;
        #pragma unroll 8
        for (int k = 0; k < 256; ++k)
            r = fmaf(Arow[k], wElem(U + 32768, k, t), r);   // (W2*W1)[i][t]
        __syncthreads();
        Arow[t] = r;
        __syncthreads();
        float s = 0.f;
        #pragma unroll 8
        for (int k = 0; k < 256; ++k)
            s = fmaf(Arow[k], wElem(U, k, t), s);           // * W0
        unsigned short h, l;
        rsplit(s, h, l);
        const int off = fragOff(i, t);
        WAh[off] = h; WAl[off] = l;
    } else {
        const int i = blockIdx.x - 256;
        unsigned short h, l;
        rsplit(wElem(U + 3 * 32768, i, t), h, l);
        const int off = fragOff(i, t);
        WBh[off] = h; WBl[off] = l;
    }
}

// ---- fused main: 512 blocks (one per h) x 1024 threads (16 waves) ----
__global__ __launch_bounds__(1024, 4)
void fused6(const float* __restrict__ src, float* __restrict__ dst,
            const unsigned short* __restrict__ WAh, const unsigned short* __restrict__ WAl,
            const unsigned short* __restrict__ WBh, const unsigned short* __restrict__ WBl)
{
    // 128 KB union: fp32 state (pass A) / MID bf16 h+l (pass B)
    __shared__ unsigned short S[65536];
    float* Sf            = (float*)S;
    unsigned short* Mh   = S;
    unsigned short* Ml   = S + 32768;

    const int t    = threadIdx.x;
    const int lane = t & 63;
    const int w    = t >> 6;            // 0..15
    const int col  = lane & 15, quad = lane >> 4;
    const int mg   = w & 3;             // m-group (4) -- W-sharing waves consecutive
    const int ng   = w >> 2;            // n-group (4)
    const size_t hbase = (size_t)blockIdx.x * 16384;

    // ============ STAGE: DMA fp32 -> LDS, source-side swizzle ============
    // instr j: rows r0 = (j>>2)*128 + w*8 + (j&3)*2, r0+1 (1 KB linear LDS).
    // lane l: lds byte (l<<4) -> logical byte-in-row = (l&31)<<4 ^ ((r&7)<<4)
    #pragma unroll
    for (int j = 0; j < 4; ++j) {       // ch = 0
        const int r0 = w * 8 + (j & 3) * 2;
        const int r  = r0 + (lane >> 5);
        const int cb = ((lane & 31) << 4) ^ ((r & 7) << 4);
        dma16(src + hbase + (size_t)r * 128 + (cb >> 2), Sf + r0 * 128);
    }
    __syncthreads();                    // ch0 resident
    #pragma unroll
    for (int j = 4; j < 8; ++j) {       // ch = 1
        const int r0 = 128 + w * 8 + (j & 3) * 2;
        const int r  = r0 + (lane >> 5);
        const int cb = ((lane & 31) << 4) ^ ((r & 7) << 4);
        dma16(src + (size_t)NSTATE + hbase + (size_t)(r & 127) * 128 + (cb >> 2),
              Sf + r0 * 128);
    }

    // ============ PASS A ============
    // m = b: 8 tiles, mg owns 2; n = kp: 16 tiles, ng owns 4.
    f32x4 acc[2][4];
    #pragma unroll
    for (int mi = 0; mi < 2; ++mi)
        #pragma unroll
        for (int nj = 0; nj < 4; ++nj) acc[mi][nj] = (f32x4)0.f;

    #pragma unroll
    for (int ks = 0; ks < 8; ++ks) {
        if (ks == 4) __syncthreads();   // ch1 DMA resident (hidden under ks 0-3)
        const int ch  = ks >> 2;
        const int cb0 = (ks & 3) * 128 + quad * 32;
        bf16x8 ah[2], al[2];
        #pragma unroll
        for (int mi = 0; mi < 2; ++mi) {
            const int r   = ch * 128 + (mg * 2 + mi) * 16 + col;
            const int swz = (r & 7) << 4;
            const char* rowp = (const char*)Sf + r * 512;
            float xv[8];
            *(float4*)&xv[0] = *(const float4*)(rowp + (cb0 ^ swz));
            *(float4*)&xv[4] = *(const float4*)(rowp + ((cb0 + 16) ^ swz));
            split8(xv, ah[mi], al[mi]);
        }
        bf16x8 bh[4], bl[4];
        #pragma unroll
        for (int nj = 0; nj < 4; ++nj) {
            const int fo = ((ng * 4 + nj) * 8 + ks) * 512 + lane * 8;
            bh[nj] = *(const bf16x8*)(WAh + fo);
            bl[nj] = *(const bf16x8*)(WAl + fo);
        }
        // term-major: same-acc update order preserved (ah*bh, al*bh, ah*bl)
        #pragma unroll
        for (int nj = 0; nj < 4; ++nj)
            #pragma unroll
            for (int mi = 0; mi < 2; ++mi)
                acc[mi][nj] = __builtin_amdgcn_mfma_f32_16x16x32_bf16(ah[mi], bh[nj], acc[mi][nj], 0, 0, 0);
        #pragma unroll
        for (int nj = 0; nj < 4; ++nj)
            #pragma unroll
            for (int mi = 0; mi < 2; ++mi)
                acc[mi][nj] = __builtin_amdgcn_mfma_f32_16x16x32_bf16(al[mi], bh[nj], acc[mi][nj], 0, 0, 0);
        #pragma unroll
        for (int nj = 0; nj < 4; ++nj)
            #pragma unroll
            for (int mi = 0; mi < 2; ++mi)
                acc[mi][nj] = __builtin_amdgcn_mfma_f32_16x16x32_bf16(ah[mi], bl[nj], acc[mi][nj], 0, 0, 0);
    }
    __syncthreads();    // all state reads complete before MID overwrites

    // ---- write MID pre-split to LDS frag layout (overwrites state region) ----
    // element (b = mt*16 + quad*4 + r, kp = nt*16 + col):
    //   frag2 = (nt&7)*8 + (nt>>3)*4 + (mt>>1); slot = col + 16*((mt*2+(quad>>1))&3)
    #pragma unroll
    for (int mi = 0; mi < 2; ++mi) {
        const int mt  = mg * 2 + mi;
        const int oct = (mt * 2 + (quad >> 1)) & 3;
        #pragma unroll
        for (int nj = 0; nj < 4; ++nj) {
            const int nt    = ng * 4 + nj;
            const int frag2 = (nt & 7) * 8 + (nt >> 3) * 4 + (mt >> 1);
            const int slot2 = col + 16 * oct;
            const int soff  = frag2 * 512 + slotSwz(frag2, slot2) * 8 + (quad & 1) * 4;
            unsigned short hhs[4], lls[4];
            #pragma unroll
            for (int r = 0; r < 4; ++r) tsplit(acc[mi][nj][r], hhs[r], lls[r]);
            bf16x4 hv = { (short)hhs[0], (short)hhs[1], (short)hhs[2], (short)hhs[3] };
            bf16x4 lv = { (short)lls[0], (short)lls[1], (short)lls[2], (short)lls[3] };
            *(bf16x4*)&Mh[soff] = hv;
            *(bf16x4*)&Ml[soff] = lv;
        }
    }
    __syncthreads();

    // ============ PASS B ============
    // m2 = ka: 8 tiles, mg owns 2; n2 = kp2: 16 tiles, ng owns 4.
    f32x4 acc2[2][4];
    #pragma unroll
    for (int mi = 0; mi < 2; ++mi)
        #pragma unroll
        for (int nj = 0; nj < 4; ++nj) acc2[mi][nj] = (f32x4)0.f;

    #pragma unroll
    for (int ks2 = 0; ks2 < 8; ++ks2) {
        bf16x8 a2h[2], a2l[2];
        #pragma unroll
        for (int mi = 0; mi < 2; ++mi) {
            const int fr = (mg * 2 + mi) * 8 + ks2;
            const int fo = fr * 512 + slotSwz(fr, lane) * 8;
            a2h[mi] = *(const bf16x8*)&Mh[fo];
            a2l[mi] = *(const bf16x8*)&Ml[fo];
        }
        bf16x8 bh2[4], bl2[4];
        #pragma unroll
        for (int nj = 0; nj < 4; ++nj) {
            const int fo = ((ng * 4 + nj) * 8 + ks2) * 512 + lane * 8;
            bh2[nj] = *(const bf16x8*)(WBh + fo);
            bl2[nj] = *(const bf16x8*)(WBl + fo);
        }
        #pragma unroll
        for (int nj = 0; nj < 4; ++nj)
            #pragma unroll
            for (int mi = 0; mi < 2; ++mi)
                acc2[mi][nj] = __builtin_amdgcn_mfma_f32_16x16x32_bf16(a2h[mi], bh2[nj], acc2[mi][nj], 0, 0, 0);
        #pragma unroll
        for (int nj = 0; nj < 4; ++nj)
            #pragma unroll
            for (int mi = 0; mi < 2; ++mi)
                acc2[mi][nj] = __builtin_amdgcn_mfma_f32_16x16x32_bf16(a2l[mi], bh2[nj], acc2[mi][nj], 0, 0, 0);
        #pragma unroll
        for (int nj = 0; nj < 4; ++nj)
            #pragma unroll
            for (int mi = 0; mi < 2; ++mi)
                acc2[mi][nj] = __builtin_amdgcn_mfma_f32_16x16x32_bf16(a2h[mi], bl2[nj], acc2[mi][nj], 0, 0, 0);
    }

    // ---- epilogue: out[ch''][kb][ka], float4 over ka (coalesced) ----
    #pragma unroll
    for (int nj = 0; nj < 4; ++nj) {
        const int kp2  = (ng * 4 + nj) * 16 + col;
        const int chpp = kp2 >> 7, kb = kp2 & 127;
        float* o = dst + (size_t)chpp * NSTATE + hbase + (size_t)kb * 128;
        #pragma unroll
        for (int mi = 0; mi < 2; ++mi) {
            const int ka = (mg * 2 + mi) * 16 + quad * 4;
            *(float4*)(o + ka) = *(float4*)&acc2[mi][nj];
        }
    }
}

extern "C" void kernel_launch(void* const* d_in, const int* in_sizes, int n_in,
                              void* d_out, int out_size, void* d_ws, size_t ws_size,
                              hipStream_t stream) {
    const float* state = (const float*)d_in[0];   // (2, 2^23)
    const float* U     = (const float*)d_in[1];   // (4, 2, 128, 128)
    float* out = (float*)d_out;

    // ws: WAh WAl WBh WBl (128 KB each, frag-linear bf16)
    unsigned short* WAh = (unsigned short*)d_ws;
    unsigned short* WAl = WAh + 65536;
    unsigned short* WBh = WAh + 2 * 65536;
    unsigned short* WBl = WAh + 3 * 65536;

    prep_all<<<512, 256, 0, stream>>>(U, WAh, WAl, WBh, WBl);
    fused6 <<<512, 1024, 0, stream>>>(state, out, WAh, WAl, WBh, WBl);
}